// Round 3
// baseline (387.496 us; speedup 1.0000x reference)
//
#include <hip/hip_runtime.h>
#include <hip/hip_bf16.h>
#include <stddef.h>

// Problem constants
#define B_   64
#define C_   1024
#define CB_  256
#define T_   512
#define G_   8
#define N_   32768          // B_*T_
#define EPS_ 1e-5f

using short8  = __attribute__((ext_vector_type(8))) short;
using short4v = __attribute__((ext_vector_type(4))) short;
using f32x4   = __attribute__((ext_vector_type(4))) float;

__device__ __forceinline__ short f2bf(float f) {
    unsigned u = __float_as_uint(f);
    u += 0x7fffu + ((u >> 16) & 1u);   // RNE
    return (short)(u >> 16);
}

__device__ __forceinline__ float mish_f(float y) {
    // mish(y) = y * tanh(softplus(y)) = y * (u^2+2u)/(u^2+2u+2), u = e^y
    float u = __expf(fminf(y, 30.f));
    float w = u * u + 2.f * u;
    return y * (w / (w + 2.f));
}

// global -> LDS direct DMA, 16 B per lane. LDS dest = wave-uniform base + lane*16.
__device__ __forceinline__ void load_lds16(const void* g, void* l) {
    __builtin_amdgcn_global_load_lds(
        (__attribute__((address_space(1))) void*)g,
        (__attribute__((address_space(3))) void*)l, 16, 0, 0);
}

// ---------------- Kernel 0: weights fp32 -> bf16 ----------------
__global__ void prep_weights(const float* __restrict__ wd, const float* __restrict__ wu,
                             short* __restrict__ wdb, short* __restrict__ wub) {
    int i = blockIdx.x * 256 + threadIdx.x;
    if (i < CB_ * C_) {
        wdb[i] = f2bf(wd[i]);
        wub[i] = f2bf(wu[i]);
    }
}

// ---------------- Kernel 1: group stats -> per-(b,c) scale/shift ----------------
__global__ void stats_kernel(const float* __restrict__ x, const float* __restrict__ gamma,
                             const float* __restrict__ beta,
                             float* __restrict__ scaleW, float* __restrict__ shiftW) {
    const int tid = threadIdx.x;
    const int bg = blockIdx.x;
    const int b = bg >> 3, g = bg & 7;
    const float4* p = (const float4*)(x + ((size_t)b * C_ + g * 128) * T_);
    float s = 0.f, q = 0.f;
#pragma unroll 4
    for (int i = tid; i < 16384; i += 256) {
        float4 v = p[i];
        s += v.x + v.y + v.z + v.w;
        q += v.x * v.x + v.y * v.y + v.z * v.z + v.w * v.w;
    }
    for (int o = 32; o > 0; o >>= 1) {
        s += __shfl_down(s, o);
        q += __shfl_down(q, o);
    }
    __shared__ float red[8];
    __shared__ float mr[2];
    const int wid = tid >> 6, lane = tid & 63;
    if (lane == 0) { red[wid] = s; red[4 + wid] = q; }
    __syncthreads();
    if (tid == 0) {
        float S = red[0] + red[1] + red[2] + red[3];
        float Q = red[4] + red[5] + red[6] + red[7];
        float mean = S * (1.f / 65536.f);
        float var = Q * (1.f / 65536.f) - mean * mean;
        mr[0] = mean;
        mr[1] = rsqrtf(var + EPS_);
    }
    __syncthreads();
    float mean = mr[0], rstd = mr[1];
    if (tid < 128) {
        int c = g * 128 + tid;
        float sc = rstd * gamma[c];
        scaleW[b * C_ + c] = sc;
        shiftW[b * C_ + c] = beta[c] - mean * sc;
    }
}

// LDS row stride 40 bf16 for the padded B tile in gemm1 (conflict-free b128 reads).
#define LDSTR 40

// ---------------- Kernel 2: GEMM1 (down-proj) + GN fused + mish ----------------
// 128x128 tile, 256 thr = 4 waves (2x2). A (weights) via global_load_lds, chunk-major
// [c][m][8k], double-buffered. B (x, needs scale/shift+bf16 in VALU) register-prefetched.
// Grid (m fastest): m-pair of same n shares x tile via L2/L3. mid stored [n][k].
__global__ __launch_bounds__(256, 2) void gemm1_mish(
    const float* __restrict__ x, const short* __restrict__ wd,
    const float* __restrict__ b_down,
    const float* __restrict__ scaleW, const float* __restrict__ shiftW,
    short* __restrict__ mid) {
    __shared__ short Abuf[2][4096];     // [c(4)][m(128)][8] = 8 KB per buffer
    __shared__ short Bs[128 * LDSTR];   // 10 KB
    __shared__ float sS[C_], sT[C_];    // 8 KB

    const int tid = threadIdx.x, lane = tid & 63, wid = tid >> 6;
    const int m0 = blockIdx.x * 128;    // 0..1 (fastest)
    const int n0 = blockIdx.y * 128;    // 0..255
    const int b  = n0 >> 9;

    for (int i = tid; i < C_; i += 256) {
        sS[i] = scaleW[b * C_ + i];
        sT[i] = shiftW[b * C_ + i];
    }

    const int b_n  = tid & 127;         // n within tile
    const int b_kh = tid >> 7;          // 0/1 -> k half (16)
    const int wm = wid >> 1, wn = wid & 1;
    const int q = lane >> 4, l16 = lane & 15;

    f32x4 acc[4][4];
#pragma unroll
    for (int i = 0; i < 4; i++)
#pragma unroll
        for (int j = 0; j < 4; j++) acc[i][j] = 0.f;

    const float* xb  = x + (size_t)b * C_ * T_ + (n0 & 511);
    const short* wdm = wd + (size_t)m0 * C_;

    float bv[16];

    // A: 8 DMA instrs per tile (4 chunks x 2 m-halves); each wave issues 2.
#define ISSUE_A(k0, bufi)                                                       \
    {                                                                           \
        _Pragma("unroll")                                                       \
        for (int u = 0; u < 2; u++) {                                           \
            int iid = wid * 2 + u, c = iid >> 1, h = iid & 1;                   \
            load_lds16(wdm + (size_t)(h * 64 + lane) * C_ + (k0) + c * 8,       \
                       &Abuf[bufi][(c * 128 + h * 64) * 8]);                    \
        }                                                                       \
    }
#define LOAD_B(k0)                                                              \
    {                                                                           \
        const float* xp = xb + (size_t)((k0) + b_kh * 16) * T_ + b_n;           \
        _Pragma("unroll")                                                       \
        for (int i = 0; i < 16; i++) bv[i] = xp[(size_t)i * T_];                \
    }
#define WRITE_B(k0)                                                             \
    {                                                                           \
        const int kb = (k0) + b_kh * 16;                                        \
        short8 v0, v1;                                                          \
        _Pragma("unroll")                                                       \
        for (int i = 0; i < 8; i++) v0[i] = f2bf(bv[i] * sS[kb + i] + sT[kb + i]); \
        _Pragma("unroll")                                                       \
        for (int i = 0; i < 8; i++) v1[i] = f2bf(bv[8 + i] * sS[kb + 8 + i] + sT[kb + 8 + i]); \
        *(short8*)&Bs[b_n * LDSTR + b_kh * 16] = v0;                            \
        *(short8*)&Bs[b_n * LDSTR + b_kh * 16 + 8] = v1;                        \
    }

    ISSUE_A(0, 0);
    LOAD_B(0);
    __syncthreads();           // sS/sT ready; vmcnt drained (A0 landed, bv ready)
    WRITE_B(0);
    __syncthreads();

    for (int kt = 0; kt < 32; ++kt) {
        if (kt < 31) {
            ISSUE_A((kt + 1) * 32, (kt + 1) & 1);
            LOAD_B((kt + 1) * 32);
        }
        const short* Ab = Abuf[kt & 1];
        short8 af[4], bfr[4];
#pragma unroll
        for (int i = 0; i < 4; i++)
            af[i] = *(const short8*)&Ab[(q * 128 + wm * 64 + i * 16 + l16) * 8];
#pragma unroll
        for (int j = 0; j < 4; j++)
            bfr[j] = *(const short8*)&Bs[(wn * 64 + j * 16 + l16) * LDSTR + q * 8];
#pragma unroll
        for (int i = 0; i < 4; i++)
#pragma unroll
            for (int j = 0; j < 4; j++)
                acc[i][j] = __builtin_amdgcn_mfma_f32_16x16x32_bf16(af[i], bfr[j], acc[i][j], 0, 0, 0);
        __syncthreads();       // all waves done reading Bs / Abuf[kt&1]
        if (kt < 31) WRITE_B((kt + 1) * 32);
        __syncthreads();       // Bs ready; vmcnt drained -> A(kt+1) landed
    }

    // epilogue: + b_down, mish, store bf16 mid[n][k] as short4 (8 B runs)
#pragma unroll
    for (int i = 0; i < 4; i++) {
        const int o0 = m0 + wm * 64 + i * 16 + q * 4;
        float bd0 = b_down[o0], bd1 = b_down[o0 + 1], bd2 = b_down[o0 + 2], bd3 = b_down[o0 + 3];
#pragma unroll
        for (int j = 0; j < 4; j++) {
            const int n = n0 + wn * 64 + j * 16 + l16;
            short4v v;
            v[0] = f2bf(mish_f(acc[i][j][0] + bd0));
            v[1] = f2bf(mish_f(acc[i][j][1] + bd1));
            v[2] = f2bf(mish_f(acc[i][j][2] + bd2));
            v[3] = f2bf(mish_f(acc[i][j][3] + bd3));
            *(short4v*)&mid[(size_t)n * CB_ + o0] = v;
        }
    }
#undef ISSUE_A
#undef LOAD_B
#undef WRITE_B
}

// ---------------- Kernel 3: GEMM2 (up-proj) + bias + residual ----------------
// Both operands via global_load_lds chunk-major, double-buffered -> ONE barrier per kt.
// mid is [n][k] (k-contiguous rows). Grid m-fastest for mid L2 reuse.
__global__ __launch_bounds__(256, 4) void gemm2_resid(
    const short* __restrict__ mid, const short* __restrict__ wu,
    const float* __restrict__ b_up, const float* __restrict__ x,
    float* __restrict__ out) {
    __shared__ short Abuf[2][4096];   // [c][m][8] 8 KB each
    __shared__ short Bbuf[2][4096];   // [c][n][8] 8 KB each

    const int tid = threadIdx.x, lane = tid & 63, wid = tid >> 6;
    const int m0 = blockIdx.x * 128;    // 0..7 (fastest)
    const int n0 = blockIdx.y * 128;    // 0..255
    const int wm = wid >> 1, wn = wid & 1;
    const int q = lane >> 4, l16 = lane & 15;

    f32x4 acc[4][4];
#pragma unroll
    for (int i = 0; i < 4; i++)
#pragma unroll
        for (int j = 0; j < 4; j++) acc[i][j] = 0.f;

    const short* wum = wu + (size_t)m0 * CB_;
    const short* mb  = mid + (size_t)n0 * CB_;

    // 16 DMA instrs per tile (A: 4 chunks x 2 halves, B: same); each wave issues 4.
#define ISSUE_AB(k0, bufi)                                                        \
    {                                                                             \
        _Pragma("unroll")                                                         \
        for (int u = 0; u < 4; u++) {                                             \
            int iid = wid * 4 + u;                                                \
            if (iid < 8) {                                                        \
                int c = iid >> 1, h = iid & 1;                                    \
                load_lds16(wum + (size_t)(h * 64 + lane) * CB_ + (k0) + c * 8,    \
                           &Abuf[bufi][(c * 128 + h * 64) * 8]);                  \
            } else {                                                              \
                int jj = iid - 8, c = jj >> 1, h = jj & 1;                        \
                load_lds16(mb + (size_t)(h * 64 + lane) * CB_ + (k0) + c * 8,     \
                           &Bbuf[bufi][(c * 128 + h * 64) * 8]);                  \
            }                                                                     \
        }                                                                         \
    }

    ISSUE_AB(0, 0);
    __syncthreads();   // vmcnt drained -> tile 0 in LDS

    for (int kt = 0; kt < 8; ++kt) {   // K=256, BK=32
        if (kt < 7) ISSUE_AB((kt + 1) * 32, (kt + 1) & 1);
        const short* Ab = Abuf[kt & 1];
        const short* Bb = Bbuf[kt & 1];
        short8 af[4], bfr[4];
#pragma unroll
        for (int i = 0; i < 4; i++)
            af[i] = *(const short8*)&Ab[(q * 128 + wm * 64 + i * 16 + l16) * 8];
#pragma unroll
        for (int j = 0; j < 4; j++)
            bfr[j] = *(const short8*)&Bb[(q * 128 + wn * 64 + j * 16 + l16) * 8];
#pragma unroll
        for (int i = 0; i < 4; i++)
#pragma unroll
            for (int j = 0; j < 4; j++)
                acc[i][j] = __builtin_amdgcn_mfma_f32_16x16x32_bf16(af[i], bfr[j], acc[i][j], 0, 0, 0);
        __syncthreads();   // reads of buf[kt&1] done (safe for kt+2) + kt+1 tile landed
    }
#undef ISSUE_AB

    // epilogue: + b_up[c] + x, fp32 store (64 B runs; L2 merges to full lines)
    const int b = n0 >> 9;
    const int t0 = n0 & 511;
#pragma unroll
    for (int i = 0; i < 4; i++) {
        const int c_b = m0 + wm * 64 + i * 16 + q * 4;
#pragma unroll
        for (int j = 0; j < 4; j++) {
            const int tt = t0 + wn * 64 + j * 16 + l16;
#pragma unroll
            for (int r = 0; r < 4; r++) {
                const int c = c_b + r;
                const size_t gi = ((size_t)b * C_ + c) * T_ + tt;
                out[gi] = acc[i][j][r] + b_up[c] + x[gi];
            }
        }
    }
}

// ---------------- Launch ----------------
extern "C" void kernel_launch(void* const* d_in, const int* in_sizes, int n_in,
                              void* d_out, int out_size, void* d_ws, size_t ws_size,
                              hipStream_t stream) {
    const float* x      = (const float*)d_in[0];
    const float* gamma  = (const float*)d_in[1];
    const float* beta   = (const float*)d_in[2];
    const float* w_down = (const float*)d_in[3];
    const float* b_down = (const float*)d_in[4];
    const float* w_up   = (const float*)d_in[5];
    const float* b_up   = (const float*)d_in[6];
    float* out = (float*)d_out;

    float* scaleW = (float*)d_ws;                       // B_*C_ floats
    float* shiftW = scaleW + B_ * C_;                   // B_*C_ floats
    short* wdb    = (short*)(shiftW + B_ * C_);         // CB_*C_ bf16
    short* wub    = wdb + CB_ * C_;                     // C_*CB_ bf16
    short* mid    = wub + C_ * CB_;                     // N_*CB_ bf16 [n][k], 16.8 MB

    prep_weights<<<dim3((CB_ * C_ + 255) / 256), 256, 0, stream>>>(w_down, w_up, wdb, wub);
    stats_kernel<<<dim3(B_ * G_), 256, 0, stream>>>(x, gamma, beta, scaleW, shiftW);
    gemm1_mish<<<dim3(2, N_ / 128), 256, 0, stream>>>(x, wdb, b_down, scaleW, shiftW, mid);
    gemm2_resid<<<dim3(C_ / 128, N_ / 128), 256, 0, stream>>>(mid, wub, b_up, x, out);
}